// Round 11
// baseline (354.734 us; speedup 1.0000x reference)
//
#include <hip/hip_runtime.h>
#include <cstdint>
#include <cstddef>

#define BATCH 4096
#define HID   2048

typedef __attribute__((ext_vector_type(8))) short bf16x8;
typedef __attribute__((ext_vector_type(4))) float f32x4;

__device__ __forceinline__ unsigned short f2bf(float f) {
  union { float f; unsigned u; } a; a.f = f;
  unsigned u = a.u;
  return (unsigned short)((u + 0x7FFFu + ((u >> 16) & 1u)) >> 16);  // RNE
}

__device__ __forceinline__ void gload_lds16(const void* g, void* l) {
  __builtin_amdgcn_global_load_lds((const __attribute__((address_space(1))) void*)g,
                                   (__attribute__((address_space(3))) void*)l, 16, 0, 0);
}

#define SCHED0() __builtin_amdgcn_sched_barrier(0)
#define SBAR()  do { SCHED0(); __builtin_amdgcn_s_barrier(); SCHED0(); } while (0)
#define WAITV(N) do { SCHED0(); asm volatile("s_waitcnt vmcnt(" #N ")" ::: "memory"); SCHED0(); } while (0)
#define WAITL(N) do { SCHED0(); asm volatile("s_waitcnt lgkmcnt(" #N ")" ::: "memory"); SCHED0(); } while (0)
#define DSR(dst, adr, IMM) asm volatile("ds_read_b128 %0, %1 offset:" #IMM : "=v"(dst) : "v"(adr))

// 16 ds_read_b128: group-(c+1) A frags (8) + B frags (8) into the given reg sets
#define RD16(AS, BS) do { \
  unsigned aA_ = aBase + (unsigned)o_n, bB_ = bBase + (unsigned)o_n; \
  DSR(AS[0],aA_,0);    DSR(AS[1],aA_,1024); DSR(AS[2],aA_,2048); DSR(AS[3],aA_,3072); \
  DSR(AS[4],aA_,4096); DSR(AS[5],aA_,5120); DSR(AS[6],aA_,6144); DSR(AS[7],aA_,7168); \
  DSR(BS[0],bB_,0);    DSR(BS[1],bB_,1024); DSR(BS[2],bB_,2048); DSR(BS[3],bB_,3072); \
  DSR(BS[4],bB_,4096); DSR(BS[5],bB_,5120); DSR(BS[6],bB_,6144); DSR(BS[7],bB_,7168); \
} while (0)

// 64 independent MFMAs (8 M-frags x 8 N-frags) on the given operand sets
#define MFMA64(AS, BS) do { _Pragma("unroll") \
  for (int m_ = 0; m_ < 8; m_++) { _Pragma("unroll") \
    for (int n_ = 0; n_ < 8; n_++) \
      acc[m_][n_] = __builtin_amdgcn_mfma_f32_16x16x32_bf16(AS[m_], BS[n_], acc[m_][n_], 0, 0, 0); } \
} while (0)

// stage one 32KB group (A 256x32 + B 256x32) into region byte-offset DOF; 8 gloads/thread
#define STAGE_G(KOFF, DOF) do { \
  gload_lds16(pA + (KOFF),          dA + (DOF)); \
  gload_lds16(pA + 262144 + (KOFF), dA + (DOF) + 4096); \
  gload_lds16(pA + 524288 + (KOFF), dA + (DOF) + 8192); \
  gload_lds16(pA + 786432 + (KOFF), dA + (DOF) + 12288); \
  gload_lds16(pB + (KOFF),          dA + (DOF) + 16384); \
  gload_lds16(pB + 65536 + (KOFF),  dA + (DOF) + 20480); \
  gload_lds16(pB + 131072 + (KOFF), dA + (DOF) + 24576); \
  gload_lds16(pB + 196608 + (KOFF), dA + (DOF) + 28672); \
} while (0)

#define ADVR(o) do { (o) = ((o) + 32768) & 131071; } while (0)

// slot c: drain stage(c+1), barrier, confirm prev reads, issue reads(c+1)+stage(c+3),
// then 64 MFMAs on group c (operands read last slot -> no intra-slot wait).
#define SLOT(VW, STG, ACUR, BCUR, ANXT, BNXT) do { \
  VW; \
  SBAR(); \
  WAITL(0); \
  RD16(ANXT, BNXT); \
  STG; \
  SCHED0(); \
  __builtin_amdgcn_s_setprio(1); MFMA64(ACUR, BCUR); __builtin_amdgcn_s_setprio(0); \
  ADVR(o_c); ADVR(o_n); ADVR(o_s); koff += 32; \
} while (0)

// ---- fp32 -> bf16 pack (verified r2): A=[x|h] 4096x4096; Wbf gate-major 8192x4096
__global__ __launch_bounds__(256) void convert_kernel(
    const float* __restrict__ x, const float* __restrict__ h,
    const float* __restrict__ wii, const float* __restrict__ wif,
    const float* __restrict__ wig, const float* __restrict__ wio,
    const float* __restrict__ whi, const float* __restrict__ whf,
    const float* __restrict__ whg, const float* __restrict__ who,
    unsigned short* __restrict__ Abf, unsigned short* __restrict__ Wbf) {
  int seg = blockIdx.y;
  const float* src;
  unsigned short* dst;
  int ofs;
  size_t rofs;
  if (seg < 4) {
    src = (seg < 2) ? x : h;
    dst = Abf;
    ofs = (seg < 2) ? 0 : 2048;
    rofs = (seg & 1) ? 2048 : 0;
    src += rofs * 2048;
  } else {
    int g = (seg - 4) & 3;
    dst = Wbf + (size_t)g * 2048 * 4096;
    ofs = (seg >= 8) ? 2048 : 0;
    rofs = 0;
    switch (seg) {
      case 4: src = wii; break; case 5: src = wif; break;
      case 6: src = wig; break; case 7: src = wio; break;
      case 8: src = whi; break; case 9: src = whf; break;
      case 10: src = whg; break; default: src = who; break;
    }
  }
  size_t idx = (size_t)blockIdx.x * 256 + threadIdx.x;
  size_t e = idx * 4;
  int n = (int)(e >> 11);
  int k = (int)(e & 2047);
  float4 v = *(const float4*)(src + e);
  ushort4 o;
  o.x = f2bf(v.x); o.y = f2bf(v.y); o.z = f2bf(v.z); o.w = f2bf(v.w);
  *(ushort4*)(dst + (rofs + (size_t)n) * 4096 + ofs + k) = o;
}

// ---- 256x256-tile LSTM GEMM, 4 waves of 128x128 (1 wave/SIMD, compute-bound
// geometry: 64 LDS reads vs 256 MFMA per slot per CU). Depth-4 ring, lead-3.
// B packed rows: p = wc*128+nf*16+lrow -> gate=nf&3, j=bn*64+wc*32+(nf>>2)*16+lrow.
__global__ __launch_bounds__(256, 1) void lstm_gemm4(
    const unsigned short* __restrict__ Abf, const unsigned short* __restrict__ Wbf,
    const float* __restrict__ c_in,
    const float* __restrict__ bias_i, const float* __restrict__ bias_f,
    const float* __restrict__ bias_g, const float* __restrict__ bias_o,
    float* __restrict__ out) {
  __shared__ unsigned short lds[4 * 16384];   // 4 regions x 32KB = 128KB

  int tid = threadIdx.x;                      // 256 threads = 4 waves
  int lane = tid & 63;
  int wid = tid >> 6;            // 0..3
  int wr = wid >> 1;             // M-half (128 rows)
  int wc = wid & 1;              // N-half (128 packed cols)
  int lrow = lane & 15;
  int qh = lane >> 4;            // 16B chunk within 32-k group

  int bid = blockIdx.x;          // 512 blocks = 16 mt x 32 bn
  int xcd = bid & 7;
  int t7 = bid >> 3;
  int mt = t7 & 15;
  int bn = xcd * 4 + (t7 >> 4);  // each XCD owns 4 bn columns
  int m0 = mt * 256;

  // staging sources: thread covers A rows r0+{0,64,128,192}, B prows r0+{0,64,128,192}
  int r0 = tid >> 2, cc0 = tid & 3;
  int ccs0 = cc0 ^ ((r0 >> 1) & 3);          // inverse-swizzled chunk (key invariant per +64 rows)
  const unsigned short* pA = Abf + (size_t)(m0 + r0) * 4096 + ccs0 * 8;
  int g0 = (r0 >> 4) & 3;                     // gate of prow r0 (invariant per +64)
  const unsigned short* pB = Wbf + ((size_t)g0 * 2048 + bn * 64 + (r0 & 15)) * 4096 + ccs0 * 8;
  // prow r0+i*64 -> wrow base + i*16 (i>>1)*32+(i&1)*16 = i*16 (verified)

  char* L0 = (char*)&lds[0];
  char* dA = L0 + tid * 16;
  unsigned ldsOff = (unsigned)(size_t)(__attribute__((address_space(3))) char*)L0;

  unsigned qs = ((unsigned)(qh ^ ((lrow >> 1) & 3))) << 4;     // swizzled chunk (bytes)
  unsigned aBase = ldsOff + (unsigned)(wr * 128 + lrow) * 64 + qs;           // + region
  unsigned bBase = ldsOff + 16384u + (unsigned)(wc * 128 + lrow) * 64 + qs;  // + region

  f32x4 acc[8][8];
  #pragma unroll
  for (int a = 0; a < 8; a++)
    #pragma unroll
    for (int b = 0; b < 8; b++) acc[a][b] = (f32x4){0.f, 0.f, 0.f, 0.f};

  bf16x8 aA[8], bA[8], aB[8], bB[8];

  int o_c = 0, o_n = 32768, o_s = 98304;     // regions of groups c, c+1, c+3
  int koff = 96;                             // k-offset (elems) of group c+3

  // ---- prologue: stage g0,g1,g2; drain g0; read g0 -> set A
  STAGE_G(0, 0);
  STAGE_G(32, 32768);
  STAGE_G(64, 65536);
  WAITV(16);
  SBAR();
  { int sv = o_n; o_n = 0; RD16(aA, bA); o_n = sv; }

  // ---- main: slots 0..123 (stage g3..g126)
  for (int i = 0; i < 62; ++i) {
    SLOT(WAITV(8), STAGE_G(koff, o_s), aA, bA, aB, bB);   // even: MFMA A, read B
    SLOT(WAITV(8), STAGE_G(koff, o_s), aB, bB, aA, bA);   // odd:  MFMA B, read A
  }
  // slot 124 (even): stage g127
  SLOT(WAITV(8), STAGE_G(koff, o_s), aA, bA, aB, bB);
  // slot 125 (odd): no stage; g126 landed via WAITV(8)
  SLOT(WAITV(8), (void)0, aB, bB, aA, bA);
  // slot 126 (even): g127 landed via WAITV(0)
  SLOT(WAITV(0), (void)0, aA, bA, aB, bB);
  // slot 127: final MFMA on set B (read at 126)
  WAITL(0);
  __builtin_amdgcn_s_setprio(1); MFMA64(aB, bB); __builtin_amdgcn_s_setprio(0);

  // ---- epilogue: gates thread-local; nf = jj2*4 + gate
  int jb = bn * 64 + wc * 32 + lrow;
  int rbase = m0 + wr * 128 + qh * 4;
  #pragma unroll
  for (int jj2 = 0; jj2 < 2; jj2++) {
    int j = jb + jj2 * 16;
    float bi = bias_i[j], bff = bias_f[j], bgg = bias_g[j], bo = bias_o[j];
    #pragma unroll
    for (int mf = 0; mf < 8; mf++) {
      #pragma unroll
      for (int qq = 0; qq < 4; qq++) {
        int m = rbase + mf * 16 + qq;       // C/D: col=lane&15, row=(lane>>4)*4+qq
        size_t off = (size_t)m * HID + j;
        float gi = acc[mf][jj2 * 4 + 0][qq] + bi;
        float gf = acc[mf][jj2 * 4 + 1][qq] + bff;
        float gg = acc[mf][jj2 * 4 + 2][qq] + bgg;
        float go = acc[mf][jj2 * 4 + 3][qq] + bo;
        float iv = 1.f / (1.f + __expf(-gi));
        float fv = 1.f / (1.f + __expf(-gf));
        float gv = tanhf(gg);
        float ov = 1.f / (1.f + __expf(-go));
        float cn = fv * c_in[off] + iv * gv;
        float hn = ov * tanhf(cn);
        out[off] = hn;
        out[(size_t)BATCH * HID + off] = cn;
      }
    }
  }
}

// ---- fallback (no workspace): round-3 verified 128-tile reg-staged kernel
__global__ __launch_bounds__(256) void lstm_gemm_fb(
    const float* __restrict__ x, const float* __restrict__ h,
    const float* __restrict__ wii, const float* __restrict__ wif,
    const float* __restrict__ wig, const float* __restrict__ wio,
    const float* __restrict__ whi, const float* __restrict__ whf,
    const float* __restrict__ whg, const float* __restrict__ who,
    const float* __restrict__ c_in,
    const float* __restrict__ bias_i, const float* __restrict__ bias_f,
    const float* __restrict__ bias_g, const float* __restrict__ bias_o,
    float* __restrict__ out) {
  __shared__ unsigned short Ald[128 * 64];
  __shared__ unsigned short Bld[128 * 64];
  int tid = threadIdx.x;
  int lane = tid & 63;
  int wid = tid >> 6;
  int wr = wid >> 1, wc = wid & 1;
  int bid = blockIdx.x;
  int swz = (bid & 7) * 256 + (bid >> 3);
  int mt = swz & 31;
  int ht = swz >> 5;
  int m0 = mt * 128;
  int j0 = ht * 32;
  f32x4 acc[4][4];
  #pragma unroll
  for (int a = 0; a < 4; a++)
    #pragma unroll
    for (int b = 0; b < 4; b++) acc[a][b] = (f32x4){0.f, 0.f, 0.f, 0.f};
  int lrow = lane & 15;
  int lsw = lrow & 7;
  int qbase = lane >> 4;
  for (int kt = 0; kt < 64; kt++) {
    int k0 = kt * 64;
    const float* Asrc = (k0 < 2048) ? x : h;
    int ka = k0 & 2047;
    #pragma unroll
    for (int i = 0; i < 4; i++) {
      int c = i * 256 + tid;
      int r = c >> 3, cc = c & 7;
      int ccs = cc ^ (r & 7);
      const float* s = Asrc + (size_t)(m0 + r) * 2048 + ka + ccs * 8;
      float4 v0 = *(const float4*)s;
      float4 v1 = *(const float4*)(s + 4);
      bf16x8 pk;
      pk[0] = (short)f2bf(v0.x); pk[1] = (short)f2bf(v0.y);
      pk[2] = (short)f2bf(v0.z); pk[3] = (short)f2bf(v0.w);
      pk[4] = (short)f2bf(v1.x); pk[5] = (short)f2bf(v1.y);
      pk[6] = (short)f2bf(v1.z); pk[7] = (short)f2bf(v1.w);
      *(bf16x8*)((char*)Ald + (size_t)c * 16) = pk;
    }
    #pragma unroll
    for (int i = 0; i < 4; i++) {
      int c = i * 256 + tid;
      int rb = c >> 3, cc = c & 7;
      int ccs = cc ^ (rb & 7);
      int g = rb >> 5, jj = rb & 31;
      const float* Bsrc;
      if (k0 < 2048) Bsrc = (g == 0) ? wii : (g == 1) ? wif : (g == 2) ? wig : wio;
      else           Bsrc = (g == 0) ? whi : (g == 1) ? whf : (g == 2) ? whg : who;
      const float* s = Bsrc + (size_t)(j0 + jj) * 2048 + ka + ccs * 8;
      float4 v0 = *(const float4*)s;
      float4 v1 = *(const float4*)(s + 4);
      bf16x8 pk;
      pk[0] = (short)f2bf(v0.x); pk[1] = (short)f2bf(v0.y);
      pk[2] = (short)f2bf(v0.z); pk[3] = (short)f2bf(v0.w);
      pk[4] = (short)f2bf(v1.x); pk[5] = (short)f2bf(v1.y);
      pk[6] = (short)f2bf(v1.z); pk[7] = (short)f2bf(v1.w);
      *(bf16x8*)((char*)Bld + (size_t)c * 16) = pk;
    }
    __syncthreads();
    #pragma unroll
    for (int ks = 0; ks < 2; ks++) {
      int q = ks * 4 + qbase;
      int qs8 = (q ^ lsw) * 8;
      bf16x8 af[4], bg[4];
      #pragma unroll
      for (int mf = 0; mf < 4; mf++)
        af[mf] = *(const bf16x8*)&Ald[(wr * 64 + mf * 16 + lrow) * 64 + qs8];
      #pragma unroll
      for (int g = 0; g < 4; g++)
        bg[g] = *(const bf16x8*)&Bld[(g * 32 + wc * 16 + lrow) * 64 + qs8];
      #pragma unroll
      for (int mf = 0; mf < 4; mf++)
        #pragma unroll
        for (int g = 0; g < 4; g++)
          acc[mf][g] = __builtin_amdgcn_mfma_f32_16x16x32_bf16(af[mf], bg[g], acc[mf][g], 0, 0, 0);
    }
    __syncthreads();
  }
  int j = j0 + wc * 16 + lrow;
  float bi = bias_i[j], bff = bias_f[j], bgg = bias_g[j], bo = bias_o[j];
  int rbase = m0 + wr * 64 + (lane >> 4) * 4;
  #pragma unroll
  for (int mf = 0; mf < 4; mf++) {
    #pragma unroll
    for (int q = 0; q < 4; q++) {
      int m = rbase + mf * 16 + q;
      size_t off = (size_t)m * HID + j;
      float gi = acc[mf][0][q] + bi;
      float gf = acc[mf][1][q] + bff;
      float gg = acc[mf][2][q] + bgg;
      float go = acc[mf][3][q] + bo;
      float iv = 1.f / (1.f + __expf(-gi));
      float fv = 1.f / (1.f + __expf(-gf));
      float gv = tanhf(gg);
      float ov = 1.f / (1.f + __expf(-go));
      float cn = fv * c_in[off] + iv * gv;
      float hn = ov * tanhf(cn);
      out[off] = hn;
      out[(size_t)BATCH * HID + off] = cn;
    }
  }
}

extern "C" void kernel_launch(void* const* d_in, const int* in_sizes, int n_in,
                              void* d_out, int out_size, void* d_ws, size_t ws_size,
                              hipStream_t stream) {
  const float* x   = (const float*)d_in[0];
  const float* h   = (const float*)d_in[1];
  const float* c   = (const float*)d_in[2];
  const float* wii = (const float*)d_in[3];
  const float* wif = (const float*)d_in[4];
  const float* wig = (const float*)d_in[5];
  const float* wio = (const float*)d_in[6];
  const float* whi = (const float*)d_in[7];
  const float* whf = (const float*)d_in[8];
  const float* whg = (const float*)d_in[9];
  const float* who = (const float*)d_in[10];
  const float* bi  = (const float*)d_in[11];
  const float* bf  = (const float*)d_in[12];
  const float* bg  = (const float*)d_in[13];
  const float* bo  = (const float*)d_in[14];
  float* out = (float*)d_out;

  size_t needA = (size_t)4096 * 4096 * 2;
  size_t needW = (size_t)8192 * 4096 * 2;

  if (ws_size >= needA + needW) {
    unsigned short* Abf = (unsigned short*)d_ws;
    unsigned short* Wbf = (unsigned short*)((char*)d_ws + needA);
    convert_kernel<<<dim3(4096, 12), 256, 0, stream>>>(
        x, h, wii, wif, wig, wio, whi, whf, whg, who, Abf, Wbf);
    lstm_gemm4<<<512, 256, 0, stream>>>(Abf, Wbf, c, bi, bf, bg, bo, out);
  } else {
    lstm_gemm_fb<<<2048, 256, 0, stream>>>(
        x, h, wii, wif, wig, wio, whi, whf, whg, who,
        c, bi, bf, bg, bo, out);
  }
}

// Round 12
// 308.501 us; speedup vs baseline: 1.1499x; 1.1499x over previous
//
#include <hip/hip_runtime.h>
#include <cstdint>
#include <cstddef>

#define BATCH 4096
#define HID   2048

typedef __attribute__((ext_vector_type(8))) short bf16x8;
typedef __attribute__((ext_vector_type(4))) float f32x4;

__device__ __forceinline__ unsigned short f2bf(float f) {
  union { float f; unsigned u; } a; a.f = f;
  unsigned u = a.u;
  return (unsigned short)((u + 0x7FFFu + ((u >> 16) & 1u)) >> 16);  // RNE
}

__device__ __forceinline__ void gload_lds16(const void* g, void* l) {
  __builtin_amdgcn_global_load_lds((const __attribute__((address_space(1))) void*)g,
                                   (__attribute__((address_space(3))) void*)l, 16, 0, 0);
}

#define SCHED0() __builtin_amdgcn_sched_barrier(0)
#define SBAR()  do { SCHED0(); __builtin_amdgcn_s_barrier(); SCHED0(); } while (0)
#define WAITV(N) do { SCHED0(); asm volatile("s_waitcnt vmcnt(" #N ")" ::: "memory"); SCHED0(); } while (0)
#define WAITL(N) do { SCHED0(); asm volatile("s_waitcnt lgkmcnt(" #N ")" ::: "memory"); SCHED0(); } while (0)
#define DSR(dst, adr, IMM) asm volatile("ds_read_b128 %0, %1 offset:" #IMM : "=v"(dst) : "v"(adr))

// A reads: 8 b128 = mf 0..3 x kk 0..1 for one M-half. Row stride 128B; mf*16 rows = 2048B; mh*64 rows = 8192B.
#define RD_A_MH0(A0, A1) do { \
  DSR(aS[0],A0,0);    DSR(aS[1],A1,0);    DSR(aS[2],A0,2048);  DSR(aS[3],A1,2048); \
  DSR(aS[4],A0,4096); DSR(aS[5],A1,4096); DSR(aS[6],A0,6144);  DSR(aS[7],A1,6144); } while (0)
#define RD_A_MH1(A0, A1) do { \
  DSR(aS[0],A0,8192);  DSR(aS[1],A1,8192);  DSR(aS[2],A0,10240); DSR(aS[3],A1,10240); \
  DSR(aS[4],A0,12288); DSR(aS[5],A1,12288); DSR(aS[6],A0,14336); DSR(aS[7],A1,14336); } while (0)
// B reads: 4 b128 = nf 0..1 x kk 0..1 for one N-half (gate pair). nf*16 prows = 2048B.
#define RD_B0(B0, B1) do { \
  DSR(bS0[0],B0,0); DSR(bS0[1],B1,0); DSR(bS0[2],B0,2048); DSR(bS0[3],B1,2048); } while (0)
#define RD_B1(B0, B1) do { \
  DSR(bS1[0],B0,4096); DSR(bS1[1],B1,4096); DSR(bS1[2],B0,6144); DSR(bS1[3],B1,6144); } while (0)

// 16 MFMA: one C-quadrant x K=64 (kk chained per acc entry)
#define MFMAQ(AS, BS, MO, NO) do { \
  _Pragma("unroll") \
  for (int mf_ = 0; mf_ < 4; mf_++) { \
    _Pragma("unroll") \
    for (int nf_ = 0; nf_ < 2; nf_++) { \
      acc[(MO)+mf_][(NO)+nf_] = __builtin_amdgcn_mfma_f32_16x16x32_bf16(AS[2*mf_],   BS[2*nf_],   acc[(MO)+mf_][(NO)+nf_], 0, 0, 0); \
      acc[(MO)+mf_][(NO)+nf_] = __builtin_amdgcn_mfma_f32_16x16x32_bf16(AS[2*mf_+1], BS[2*nf_+1], acc[(MO)+mf_][(NO)+nf_], 0, 0, 0); \
    } } } while (0)

#define PRIO1() __builtin_amdgcn_s_setprio(1)
#define PRIO0() __builtin_amdgcn_s_setprio(0)

// stage one A half-tile (128 rows x 64K = 16KB): 2 gloads/thread. H in {0,1}, KO in elems.
#define ST_AH(BUF, H, KO) do { \
  gload_lds16(pA0 + (size_t)(H) * 524288 + (KO),          dD + (BUF) * 65536 + (H) * 16384); \
  gload_lds16(pA0 + (size_t)(H) * 524288 + 262144 + (KO), dD + (BUF) * 65536 + (H) * 16384 + 8192); } while (0)
// stage one B half-tile (128 prows x 64K = 16KB): wc-step = 16 wrows = 65536 elems.
#define ST_BH(BUF, H, KO) do { \
  gload_lds16(pB0 + (size_t)(H) * 131072 + (KO),         dD + (BUF) * 65536 + 32768 + (H) * 16384); \
  gload_lds16(pB0 + (size_t)(H) * 131072 + 65536 + (KO), dD + (BUF) * 65536 + 32768 + (H) * 16384 + 8192); } while (0)

// ---- fp32 -> bf16 pack (verified r2): A=[x|h] 4096x4096; Wbf gate-major 8192x4096
__global__ __launch_bounds__(256) void convert_kernel(
    const float* __restrict__ x, const float* __restrict__ h,
    const float* __restrict__ wii, const float* __restrict__ wif,
    const float* __restrict__ wig, const float* __restrict__ wio,
    const float* __restrict__ whi, const float* __restrict__ whf,
    const float* __restrict__ whg, const float* __restrict__ who,
    unsigned short* __restrict__ Abf, unsigned short* __restrict__ Wbf) {
  int seg = blockIdx.y;
  const float* src;
  unsigned short* dst;
  int ofs;
  size_t rofs;
  if (seg < 4) {
    src = (seg < 2) ? x : h;
    dst = Abf;
    ofs = (seg < 2) ? 0 : 2048;
    rofs = (seg & 1) ? 2048 : 0;
    src += rofs * 2048;
  } else {
    int g = (seg - 4) & 3;
    dst = Wbf + (size_t)g * 2048 * 4096;
    ofs = (seg >= 8) ? 2048 : 0;
    rofs = 0;
    switch (seg) {
      case 4: src = wii; break; case 5: src = wif; break;
      case 6: src = wig; break; case 7: src = wio; break;
      case 8: src = whi; break; case 9: src = whf; break;
      case 10: src = whg; break; default: src = who; break;
    }
  }
  size_t idx = (size_t)blockIdx.x * 256 + threadIdx.x;
  size_t e = idx * 4;
  int n = (int)(e >> 11);
  int k = (int)(e & 2047);
  float4 v = *(const float4*)(src + e);
  ushort4 o;
  o.x = f2bf(v.x); o.y = f2bf(v.y); o.z = f2bf(v.z); o.w = f2bf(v.w);
  *(ushort4*)(dst + (rofs + (size_t)n) * 4096 + ofs + k) = o;
}

// ---- 256x256-tile LSTM GEMM, faithful m201 8-phase schedule:
// phase = C-quadrant x K64; reads 12/4/8/0; stage 1 half-tile/phase (safe-ordered);
// vmcnt(4) once per K-tile (P4/P8); 2 barriers/phase; full 8-row XOR swizzle.
__global__ __launch_bounds__(512, 2) void lstm_gemm8(
    const unsigned short* __restrict__ Abf, const unsigned short* __restrict__ Wbf,
    const float* __restrict__ c_in,
    const float* __restrict__ bias_i, const float* __restrict__ bias_f,
    const float* __restrict__ bias_g, const float* __restrict__ bias_o,
    float* __restrict__ out) {
  // 2 buf x (A 256x64 32KB + B 256x64 32KB) = 128KB; rows 128B, swizzle chunk^=(row&7)
  __shared__ unsigned short lds[2 * 32768];

  int tid = threadIdx.x;
  int lane = tid & 63;
  int wid = tid >> 6;            // 0..7
  int wr = wid >> 2;             // M-half of block (128 rows)
  int wc = wid & 3;              // N-quarter (64 packed prows)
  int lrow = lane & 15;
  int qh = lane >> 4;            // 0..3

  int bid = blockIdx.x;          // 512 blocks = 16 mt x 32 bn
  int xcd = bid & 7;
  int t7 = bid >> 3;
  int mt = t7 & 15;
  int bn = xcd * 4 + (t7 >> 4);
  int m0 = mt * 256;

  // staging sources (8 chunks/row): r0 = tid>>3 (0..63), cc0 = tid&7
  int r0 = tid >> 3, cc0 = tid & 7;
  int ccs0 = cc0 ^ (r0 & 7);     // inverse-swizzle; key invariant under +64/+128 rows
  const unsigned short* pA0 = Abf + (size_t)(m0 + r0) * 4096 + ccs0 * 8;
  int g0 = (r0 >> 4) & 3;
  const unsigned short* pB0 = Wbf + ((size_t)g0 * 2048 + bn * 64 + (r0 & 15)) * 4096 + ccs0 * 8;

  char* L0 = (char*)&lds[0];
  char* dD = L0 + tid * 16;
  unsigned ldsOff = (unsigned)(size_t)(__attribute__((address_space(3))) char*)L0;

  // read addresses: key = lrow&7; chunk kk0 = qh^key, kk1 = (qh^key)^4
  int key = lrow & 7;
  unsigned c0 = (unsigned)(qh ^ key) * 16u;
  unsigned c1 = c0 ^ 64u;
  unsigned aRow = (unsigned)(wr * 128 + lrow) * 128u;
  unsigned bRow = 32768u + (unsigned)(wc * 64 + lrow) * 128u;
  unsigned aAd00 = ldsOff + aRow + c0, aAd01 = ldsOff + aRow + c1;            // buf0
  unsigned aAd10 = aAd00 + 65536u,     aAd11 = aAd01 + 65536u;                // buf1
  unsigned bAd00 = ldsOff + bRow + c0, bAd01 = ldsOff + bRow + c1;
  unsigned bAd10 = bAd00 + 65536u,     bAd11 = bAd01 + 65536u;

  f32x4 acc[8][4];
  #pragma unroll
  for (int a = 0; a < 8; a++)
    #pragma unroll
    for (int b = 0; b < 4; b++) acc[a][b] = (f32x4){0.f, 0.f, 0.f, 0.f};

  bf16x8 aS[8], bS0[4], bS1[4];

  // ---- prologue: tile0 full (buf0), tile1 B halves (buf1); drain tile0, keep t1B
  ST_AH(0, 0, 0); ST_AH(0, 1, 0);
  ST_BH(0, 0, 0); ST_BH(0, 1, 0);
  ST_BH(1, 0, 64); ST_BH(1, 1, 64);
  WAITV(4);
  SBAR();

  // ---- main: 31 iters, tiles e=2i (buf0), o=2i+1 (buf1); stages A(o), B(e+2), A(e+2), B(o+2)
  for (int i = 0; i < 31; ++i) {
    int koO = i * 128 + 64;      // tile o
    int koN = i * 128 + 128;     // tile e+2
    int koN2 = i * 128 + 192;    // tile o+2
    // P1 (mh0,nh0 | buf0): 12 reads; stage A-h0(o)
    RD_A_MH0(aAd00, aAd01); RD_B0(bAd00, bAd01);
    ST_AH(1, 0, koO);
    SBAR(); WAITL(0);
    PRIO1(); MFMAQ(aS, bS0, 0, 0); PRIO0();
    SBAR();
    // P2 (mh0,nh1): 4 reads; stage A-h1(o)
    RD_B1(bAd00, bAd01);
    ST_AH(1, 1, koO);
    SBAR(); WAITL(0);
    PRIO1(); MFMAQ(aS, bS1, 0, 2); PRIO0();
    SBAR();
    // P3 (mh1,nh0): 8 reads; stage B-h0(e+2)
    RD_A_MH1(aAd00, aAd01);
    ST_BH(0, 0, koN);
    SBAR(); WAITL(0);
    PRIO1(); MFMAQ(aS, bS0, 4, 0); PRIO0();
    SBAR();
    // P4 (mh1,nh1): 0 reads; stage B-h1(e+2); vmcnt(4) lands tile o
    ST_BH(0, 1, koN);
    SBAR();
    PRIO1(); MFMAQ(aS, bS1, 4, 2); PRIO0();
    WAITV(4);
    SBAR();
    // P5 (mh0,nh0 | buf1): 12 reads; stage A-h0(e+2)
    RD_A_MH0(aAd10, aAd11); RD_B0(bAd10, bAd11);
    ST_AH(0, 0, koN);
    SBAR(); WAITL(0);
    PRIO1(); MFMAQ(aS, bS0, 0, 0); PRIO0();
    SBAR();
    // P6 (mh0,nh1): 4 reads; stage A-h1(e+2)
    RD_B1(bAd10, bAd11);
    ST_AH(0, 1, koN);
    SBAR(); WAITL(0);
    PRIO1(); MFMAQ(aS, bS1, 0, 2); PRIO0();
    SBAR();
    // P7 (mh1,nh0): 8 reads; stage B-h0(o+2)
    RD_A_MH1(aAd10, aAd11);
    ST_BH(1, 0, koN2);
    SBAR(); WAITL(0);
    PRIO1(); MFMAQ(aS, bS0, 4, 0); PRIO0();
    SBAR();
    // P8 (mh1,nh1): 0 reads; stage B-h1(o+2); vmcnt(4) lands tile e+2
    ST_BH(1, 1, koN2);
    SBAR();
    PRIO1(); MFMAQ(aS, bS1, 4, 2); PRIO0();
    WAITV(4);
    SBAR();
  }

  // ---- peeled iter 31: tiles 62 (buf0), 63 (buf1); stage only A(63); vmcnt(0) at P4
  {
    RD_A_MH0(aAd00, aAd01); RD_B0(bAd00, bAd01);
    ST_AH(1, 0, 4032);
    SBAR(); WAITL(0);
    PRIO1(); MFMAQ(aS, bS0, 0, 0); PRIO0();
    SBAR();
    RD_B1(bAd00, bAd01);
    ST_AH(1, 1, 4032);
    SBAR(); WAITL(0);
    PRIO1(); MFMAQ(aS, bS1, 0, 2); PRIO0();
    SBAR();
    RD_A_MH1(aAd00, aAd01);
    SBAR(); WAITL(0);
    PRIO1(); MFMAQ(aS, bS0, 4, 0); PRIO0();
    SBAR();
    SBAR();
    PRIO1(); MFMAQ(aS, bS1, 4, 2); PRIO0();
    WAITV(0);
    SBAR();
    RD_A_MH0(aAd10, aAd11); RD_B0(bAd10, bAd11);
    SBAR(); WAITL(0);
    PRIO1(); MFMAQ(aS, bS0, 0, 0); PRIO0();
    SBAR();
    RD_B1(bAd10, bAd11);
    SBAR(); WAITL(0);
    PRIO1(); MFMAQ(aS, bS1, 0, 2); PRIO0();
    SBAR();
    RD_A_MH1(aAd10, aAd11);
    SBAR(); WAITL(0);
    PRIO1(); MFMAQ(aS, bS0, 4, 0); PRIO0();
    SBAR();
    PRIO1(); MFMAQ(aS, bS1, 4, 2); PRIO0();
  }

  // ---- epilogue: gates thread-local (acc n-index = gate); acc row a -> M row a*16
  int j = bn * 64 + wc * 16 + lrow;
  float bi = bias_i[j], bff = bias_f[j], bgg = bias_g[j], bo = bias_o[j];
  int rbase = m0 + wr * 128 + qh * 4;
  #pragma unroll
  for (int mf = 0; mf < 8; mf++) {
    #pragma unroll
    for (int qq = 0; qq < 4; qq++) {
      int m = rbase + mf * 16 + qq;     // C/D: col=lane&15, row=(lane>>4)*4+qq
      size_t off = (size_t)m * HID + j;
      float gi = acc[mf][0][qq] + bi;
      float gf = acc[mf][1][qq] + bff;
      float gg = acc[mf][2][qq] + bgg;
      float go = acc[mf][3][qq] + bo;
      float iv = 1.f / (1.f + __expf(-gi));
      float fv = 1.f / (1.f + __expf(-gf));
      float gv = tanhf(gg);
      float ov = 1.f / (1.f + __expf(-go));
      float cn = fv * c_in[off] + iv * gv;
      float hn = ov * tanhf(cn);
      out[off] = hn;
      out[(size_t)BATCH * HID + off] = cn;
    }
  }
}

// ---- fallback (no workspace): round-3 verified 128-tile reg-staged kernel
__global__ __launch_bounds__(256) void lstm_gemm_fb(
    const float* __restrict__ x, const float* __restrict__ h,
    const float* __restrict__ wii, const float* __restrict__ wif,
    const float* __restrict__ wig, const float* __restrict__ wio,
    const float* __restrict__ whi, const float* __restrict__ whf,
    const float* __restrict__ whg, const float* __restrict__ who,
    const float* __restrict__ c_in,
    const float* __restrict__ bias_i, const float* __restrict__ bias_f,
    const float* __restrict__ bias_g, const float* __restrict__ bias_o,
    float* __restrict__ out) {
  __shared__ unsigned short Ald[128 * 64];
  __shared__ unsigned short Bld[128 * 64];
  int tid = threadIdx.x;
  int lane = tid & 63;
  int wid = tid >> 6;
  int wr = wid >> 1, wc = wid & 1;
  int bid = blockIdx.x;
  int swz = (bid & 7) * 256 + (bid >> 3);
  int mt = swz & 31;
  int ht = swz >> 5;
  int m0 = mt * 128;
  int j0 = ht * 32;
  f32x4 acc[4][4];
  #pragma unroll
  for (int a = 0; a < 4; a++)
    #pragma unroll
    for (int b = 0; b < 4; b++) acc[a][b] = (f32x4){0.f, 0.f, 0.f, 0.f};
  int lrow = lane & 15;
  int lsw = lrow & 7;
  int qbase = lane >> 4;
  for (int kt = 0; kt < 64; kt++) {
    int k0 = kt * 64;
    const float* Asrc = (k0 < 2048) ? x : h;
    int ka = k0 & 2047;
    #pragma unroll
    for (int i = 0; i < 4; i++) {
      int c = i * 256 + tid;
      int r = c >> 3, cc = c & 7;
      int ccs = cc ^ (r & 7);
      const float* s = Asrc + (size_t)(m0 + r) * 2048 + ka + ccs * 8;
      float4 v0 = *(const float4*)s;
      float4 v1 = *(const float4*)(s + 4);
      bf16x8 pk;
      pk[0] = (short)f2bf(v0.x); pk[1] = (short)f2bf(v0.y);
      pk[2] = (short)f2bf(v0.z); pk[3] = (short)f2bf(v0.w);
      pk[4] = (short)f2bf(v1.x); pk[5] = (short)f2bf(v1.y);
      pk[6] = (short)f2bf(v1.z); pk[7] = (short)f2bf(v1.w);
      *(bf16x8*)((char*)Ald + (size_t)c * 16) = pk;
    }
    #pragma unroll
    for (int i = 0; i < 4; i++) {
      int c = i * 256 + tid;
      int rb = c >> 3, cc = c & 7;
      int ccs = cc ^ (rb & 7);
      int g = rb >> 5, jj = rb & 31;
      const float* Bsrc;
      if (k0 < 2048) Bsrc = (g == 0) ? wii : (g == 1) ? wif : (g == 2) ? wig : wio;
      else           Bsrc = (g == 0) ? whi : (g == 1) ? whf : (g == 2) ? whg : who;
      const float* s = Bsrc + (size_t)(j0 + jj) * 2048 + ka + ccs * 8;
      float4 v0 = *(const float4*)s;
      float4 v1 = *(const float4*)(s + 4);
      bf16x8 pk;
      pk[0] = (short)f2bf(v0.x); pk[1] = (short)f2bf(v0.y);
      pk[2] = (short)f2bf(v0.z); pk[3] = (short)f2bf(v0.w);
      pk[4] = (short)f2bf(v1.x); pk[5] = (short)f2bf(v1.y);
      pk[6] = (short)f2bf(v1.z); pk[7] = (short)f2bf(v1.w);
      *(bf16x8*)((char*)Bld + (size_t)c * 16) = pk;
    }
    __syncthreads();
    #pragma unroll
    for (int ks = 0; ks < 2; ks++) {
      int q = ks * 4 + qbase;
      int qs8 = (q ^ lsw) * 8;
      bf16x8 af[4], bg[4];
      #pragma unroll
      for (int mf = 0; mf < 4; mf++)
        af[mf] = *(const bf16x8*)&Ald[(wr * 64 + mf * 16 + lrow) * 64 + qs8];
      #pragma unroll
      for (int g = 0; g < 4; g++)
        bg[g] = *(const bf16x8*)&Bld[(g * 32 + wc * 16 + lrow) * 64 + qs8];
      #pragma unroll
      for (int mf = 0; mf < 4; mf++)
        #pragma unroll
        for (int g = 0; g < 4; g++)
          acc[mf][g] = __builtin_amdgcn_mfma_f32_16x16x32_bf16(af[mf], bg[g], acc[mf][g], 0, 0, 0);
    }
    __syncthreads();
  }
  int j = j0 + wc * 16 + lrow;
  float bi = bias_i[j], bff = bias_f[j], bgg = bias_g[j], bo = bias_o[j];
  int rbase = m0 + wr * 64 + (lane >> 4) * 4;
  #pragma unroll
  for (int mf = 0; mf < 4; mf++) {
    #pragma unroll
    for (int q = 0; q < 4; q++) {
      int m = rbase + mf * 16 + q;
      size_t off = (size_t)m * HID + j;
      float gi = acc[mf][0][q] + bi;
      float gf = acc[mf][1][q] + bff;
      float gg = acc[mf][2][q] + bgg;
      float go = acc[mf][3][q] + bo;
      float iv = 1.f / (1.f + __expf(-gi));
      float fv = 1.f / (1.f + __expf(-gf));
      float gv = tanhf(gg);
      float ov = 1.f / (1.f + __expf(-go));
      float cn = fv * c_in[off] + iv * gv;
      float hn = ov * tanhf(cn);
      out[off] = hn;
      out[(size_t)BATCH * HID + off] = cn;
    }
  }
}

extern "C" void kernel_launch(void* const* d_in, const int* in_sizes, int n_in,
                              void* d_out, int out_size, void* d_ws, size_t ws_size,
                              hipStream_t stream) {
  const float* x   = (const float*)d_in[0];
  const float* h   = (const float*)d_in[1];
  const float* c   = (const float*)d_in[2];
  const float* wii = (const float*)d_in[3];
  const float* wif = (const float*)d_in[4];
  const float* wig = (const float*)d_in[5];
  const float* wio = (const float*)d_in[6];
  const float* whi = (const float*)d_in[7];
  const float* whf = (const float*)d_in[8];
  const float* whg = (const float*)d_in[9];
  const float* who = (const float*)d_in[10];
  const float* bi  = (const float*)d_in[11];
  const float* bf  = (const float*)d_in[12];
  const float* bg  = (const float*)d_in[13];
  const float* bo  = (const float*)d_in[14];
  float* out = (float*)d_out;

  size_t needA = (size_t)4096 * 4096 * 2;
  size_t needW = (size_t)8192 * 4096 * 2;

  if (ws_size >= needA + needW) {
    unsigned short* Abf = (unsigned short*)d_ws;
    unsigned short* Wbf = (unsigned short*)((char*)d_ws + needA);
    convert_kernel<<<dim3(4096, 12), 256, 0, stream>>>(
        x, h, wii, wif, wig, wio, whi, whf, whg, who, Abf, Wbf);
    lstm_gemm8<<<512, 512, 0, stream>>>(Abf, Wbf, c, bi, bf, bg, bo, out);
  } else {
    lstm_gemm_fb<<<2048, 256, 0, stream>>>(
        x, h, wii, wif, wig, wio, whi, whf, whg, who,
        c, bi, bf, bg, bo, out);
  }
}